// Round 3
// baseline (387.605 us; speedup 1.0000x reference)
//
#include <hip/hip_runtime.h>
#include <stdint.h>

typedef unsigned short u16;
typedef __attribute__((ext_vector_type(8))) short bf16x8;
typedef __attribute__((ext_vector_type(4))) float f32x4;

__device__ __forceinline__ u16 f2bf(float f) {
  union { float f; unsigned u; } x; x.f = f;
  unsigned r = x.u + 0x7fffu + ((x.u >> 16) & 1u);
  return (u16)(r >> 16);
}

#define GLOAD16(g, l) __builtin_amdgcn_global_load_lds( \
    (const __attribute__((address_space(1))) unsigned int*)(g), \
    (__attribute__((address_space(3))) unsigned int*)(l), 16, 0, 0)

// ---------------- weight transpose fp32[K,N] -> bf16[N,K] ----------------
__global__ __launch_bounds__(256) void wt_kernel(const float* __restrict__ W,
                                                 u16* __restrict__ Wt, int K, int N) {
  __shared__ float tile[32][33];
  int tx = threadIdx.x & 31, ty = threadIdx.x >> 5;
  int n0 = blockIdx.x * 32, k0 = blockIdx.y * 32;
#pragma unroll
  for (int i = 0; i < 32; i += 8)
    tile[ty + i][tx] = W[(size_t)(k0 + ty + i) * N + n0 + tx];
  __syncthreads();
#pragma unroll
  for (int i = 0; i < 32; i += 8)
    Wt[(size_t)(n0 + ty + i) * K + k0 + tx] = f2bf(tile[tx][ty + i]);
}

// ---------------- LayerNorm fp32 -> bf16, D=1024 ----------------
__global__ __launch_bounds__(256) void ln_kernel(const float* __restrict__ x,
                                                 const float* __restrict__ g,
                                                 const float* __restrict__ be,
                                                 u16* __restrict__ out) {
  int row = blockIdx.x, t = threadIdx.x;
  const float4 v = ((const float4*)(x + (size_t)row * 1024))[t];
  float s = v.x + v.y + v.z + v.w;
#pragma unroll
  for (int m = 1; m < 64; m <<= 1) s += __shfl_xor(s, m);
  __shared__ float p1[4], p2[4];
  int wid = t >> 6, lane = t & 63;
  if (lane == 0) p1[wid] = s;
  __syncthreads();
  float mean = (p1[0] + p1[1] + p1[2] + p1[3]) * (1.f / 1024.f);
  float a0 = v.x - mean, a1 = v.y - mean, a2 = v.z - mean, a3 = v.w - mean;
  float ss = a0 * a0 + a1 * a1 + a2 * a2 + a3 * a3;
#pragma unroll
  for (int m = 1; m < 64; m <<= 1) ss += __shfl_xor(ss, m);
  if (lane == 0) p2[wid] = ss;
  __syncthreads();
  float var = (p2[0] + p2[1] + p2[2] + p2[3]) * (1.f / 1024.f);
  float rs = rsqrtf(var + 1e-5f);
  const float4 gg = ((const float4*)g)[t];
  const float4 bb = ((const float4*)be)[t];
  ushort4 ov;
  ov.x = f2bf(a0 * rs * gg.x + bb.x);
  ov.y = f2bf(a1 * rs * gg.y + bb.y);
  ov.z = f2bf(a2 * rs * gg.z + bb.z);
  ov.w = f2bf(a3 * rs * gg.w + bb.w);
  *(ushort4*)(out + (size_t)row * 1024 + t * 4) = ov;
}

// ---------------- bf16 MFMA GEMM: C[M,N] = A[M,K] * Bt[N,K]^T + bias ----------------
// 128x128 tile, BK=64, 4 waves (2x2), global_load_lds w=16, XOR-swizzled LDS.
template <int GELU_F, int HAS_RES, int OUT_F32, int OUT_BF16>
__global__ __launch_bounds__(256) void gemm_kernel(
    const u16* __restrict__ A, const u16* __restrict__ Bt,
    const float* __restrict__ bias, const float* __restrict__ res,
    float* __restrict__ outf, u16* __restrict__ outb, int M, int N, int K) {
  __shared__ u16 lA[128 * 64];
  __shared__ u16 lB[128 * 64];
  const int t = threadIdx.x, lane = t & 63, wid = t >> 6;
  const int bm = blockIdx.x, bn = blockIdx.y;
  const int wr = wid >> 1, wc = wid & 1;
  f32x4 acc[4][4] = {};

  const int nkt = K >> 6;
  for (int kt = 0; kt < nkt; ++kt) {
#pragma unroll
    for (int r = 0; r < 4; ++r) {
      int f = (r * 256 + t) * 16;                 // linear LDS byte offset
      int fs = f ^ (((f >> 7) & 7) << 4);         // inverse-swizzled source
      int row = fs >> 7;                          // 0..127
      int kb = (fs & 127) >> 1;                   // bf16 col, multiple of 8
      const u16* gA = A + (size_t)(bm * 128 + row) * K + kt * 64 + kb;
      const u16* gB = Bt + (size_t)(bn * 128 + row) * K + kt * 64 + kb;
      GLOAD16(gA, ((char*)lA) + (r * 256 + wid * 64) * 16);
      GLOAD16(gB, ((char*)lB) + (r * 256 + wid * 64) * 16);
    }
    __syncthreads();
#pragma unroll
    for (int kk = 0; kk < 2; ++kk) {
      bf16x8 af[4], bfr[4];
#pragma unroll
      for (int fm = 0; fm < 4; ++fm) {
        int row = wr * 64 + fm * 16 + (lane & 15);
        int k = kk * 32 + (lane >> 4) * 8;
        af[fm] = *(const bf16x8*)((const char*)lA + ((row * 128 + k * 2) ^ ((row & 7) << 4)));
      }
#pragma unroll
      for (int fn = 0; fn < 4; ++fn) {
        int row = wc * 64 + fn * 16 + (lane & 15);
        int k = kk * 32 + (lane >> 4) * 8;
        bfr[fn] = *(const bf16x8*)((const char*)lB + ((row * 128 + k * 2) ^ ((row & 7) << 4)));
      }
#pragma unroll
      for (int fm = 0; fm < 4; ++fm)
#pragma unroll
        for (int fn = 0; fn < 4; ++fn)
          acc[fm][fn] = __builtin_amdgcn_mfma_f32_16x16x32_bf16(af[fm], bfr[fn], acc[fm][fn], 0, 0, 0);
    }
    __syncthreads();
  }

#pragma unroll
  for (int fm = 0; fm < 4; ++fm) {
#pragma unroll
    for (int fn = 0; fn < 4; ++fn) {
      int col = bn * 128 + wc * 64 + fn * 16 + (lane & 15);
      float bcol = bias[col];
#pragma unroll
      for (int r = 0; r < 4; ++r) {
        int row = bm * 128 + wr * 64 + fm * 16 + (lane >> 4) * 4 + r;
        float v = acc[fm][fn][r] + bcol;
        if constexpr (GELU_F) v = 0.5f * v * (1.0f + erff(v * 0.70710678118654752f));
        size_t idx = (size_t)row * N + col;
        if constexpr (HAS_RES) v += res[idx];
        if constexpr (OUT_F32) outf[idx] = v;
        if constexpr (OUT_BF16) outb[idx] = f2bf(v);
      }
    }
  }
}

// ---------------- attention: ALiBi sliding-window causal, MFMA ----------------
// grid: (qtile 0..31, bh 0..31); block 256 = 4 waves, each wave 16 queries.
// NaN-proof: finite sentinel; lV staged for ALL key indices PV reads (0..335).
__global__ __launch_bounds__(256) void attn_kernel(const u16* __restrict__ qkv,
                                                   u16* __restrict__ o) {
  __shared__ u16 lK[320 * 64];      // K rows [key][hd], XOR-swizzled, 40KB
  __shared__ u16 lV[64 * 344];      // V transposed [hd][key 0..336 +pad], 43KB
  __shared__ u16 lP[4][16 * 296];   // per-wave P [q][key 288], padded, 37KB
  const int t = threadIdx.x, lane = t & 63, w = t >> 6;
  const int qtile = blockIdx.x, bh = blockIdx.y, b = bh >> 4, h = bh & 15;
  const int kbase = qtile * 64 - 256;
  const size_t bq = (size_t)b * 2048 * 3072;
  const float NEGBIG = -1e30f;

  // ---- stage K (swizzled, keys 0..319) and V^T (keys 0..335, zero-filled) ----
  for (int r = 0; r < 11; ++r) {
    int jl = r * 32 + (t >> 3);      // 0..351
    int d0 = (t & 7) * 8;
    int jg = kbase + jl;
    if (jl < 336) {
      uint4 vv;
      if (jg >= 0 && jg < 2048)
        vv = *(const uint4*)(qkv + bq + (size_t)jg * 3072 + 2048 + h * 64 + d0);
      else
        vv = make_uint4(0, 0, 0, 0);
      const u16* vs = (const u16*)&vv;
#pragma unroll
      for (int u = 0; u < 8; ++u) lV[(d0 + u) * 344 + jl] = vs[u];
      if (jl < 320) {
        uint4 kv;
        if (jg >= 0 && jg < 2048)
          kv = *(const uint4*)(qkv + bq + (size_t)jg * 3072 + 1024 + h * 64 + d0);
        else
          kv = make_uint4(0, 0, 0, 0);
        *(uint4*)((char*)lK + ((jl * 128 + d0 * 2) ^ ((jl & 7) << 4))) = kv;
      }
    }
  }
  __syncthreads();

  const int i0 = qtile * 64 + w * 16;
  const int q15 = lane & 15, grp = lane >> 4;
  // Q fragments in registers (B-operand of S^T mfma)
  const u16* qrow = qkv + bq + (size_t)(i0 + q15) * 3072 + h * 64;
  bf16x8 qf0 = *(const bf16x8*)(qrow + grp * 8);
  bf16x8 qf1 = *(const bf16x8*)(qrow + 32 + grp * 8);

  // ---- S^T = K * Q^T over 17 key tiles ----
  f32x4 st[17];
#pragma unroll
  for (int tt = 0; tt < 17; ++tt) {
    st[tt] = f32x4{0.f, 0.f, 0.f, 0.f};
    int klb = w * 16 + tt * 16;
#pragma unroll
    for (int kk = 0; kk < 2; ++kk) {
      int row = klb + q15;
      int k = kk * 32 + grp * 8;
      bf16x8 kf = *(const bf16x8*)((const char*)lK + ((row * 128 + k * 2) ^ ((row & 7) << 4)));
      st[tt] = __builtin_amdgcn_mfma_f32_16x16x32_bf16(kf, (kk ? qf1 : qf0), st[tt], 0, 0, 0);
    }
  }

  // ---- mask + alibi + softmax (reduce over keys: regs, tiles, lane-groups) ----
  const float slope = exp2f(-0.5f * (float)(h + 1));
  const int qg = i0 + q15;
  float mx = NEGBIG;
#pragma unroll
  for (int tt = 0; tt < 17; ++tt) {
    int kb = kbase + w * 16 + tt * 16;
#pragma unroll
    for (int r = 0; r < 4; ++r) {
      int key = kb + grp * 4 + r;
      float s = st[tt][r] * 0.125f + slope * (float)(key - qg);
      bool valid = (key >= 0) && (key <= qg) && (qg - key < 256);
      s = valid ? s : NEGBIG;
      st[tt][r] = s;
      mx = fmaxf(mx, s);
    }
  }
  mx = fmaxf(mx, __shfl_xor(mx, 16));
  mx = fmaxf(mx, __shfl_xor(mx, 32));
  float sum = 0.f;
#pragma unroll
  for (int tt = 0; tt < 17; ++tt)
#pragma unroll
    for (int r = 0; r < 4; ++r) {
      float p = __expf(st[tt][r] - mx);   // sentinel - finite -> underflow -> 0
      st[tt][r] = p;
      sum += p;
    }
  sum += __shfl_xor(sum, 16);
  sum += __shfl_xor(sum, 32);
  const float inv = 1.0f / sum;           // sum >= 1 (diagonal always valid)

  // ---- write P (bf16, unnormalized) to per-wave LDS, A-layout-friendly ----
  u16* Pw = &lP[w][0];
#pragma unroll
  for (int tt = 0; tt < 17; ++tt) {
    unsigned u0 = ((unsigned)f2bf(st[tt][1]) << 16) | f2bf(st[tt][0]);
    unsigned u1 = ((unsigned)f2bf(st[tt][3]) << 16) | f2bf(st[tt][2]);
    uint2 uu; uu.x = u0; uu.y = u1;
    *(uint2*)(Pw + q15 * 296 + tt * 16 + grp * 4) = uu;
  }
  { uint2 z; z.x = 0; z.y = 0; *(uint2*)(Pw + q15 * 296 + 272 + grp * 4) = z; }

  // ---- O^T = V^T * P^T over 9 key chunks of 32 ----
  f32x4 ot[4] = {};
#pragma unroll
  for (int c = 0; c < 9; ++c) {
    bf16x8 pf = *(const bf16x8*)(Pw + q15 * 296 + c * 32 + grp * 8);
#pragma unroll
    for (int hb = 0; hb < 4; ++hb) {
      bf16x8 vf = *(const bf16x8*)(lV + (hb * 16 + q15) * 344 + w * 16 + c * 32 + grp * 8);
      ot[hb] = __builtin_amdgcn_mfma_f32_16x16x32_bf16(vf, pf, ot[hb], 0, 0, 0);
    }
  }

  // ---- normalize + store O (bf16 [4096][1024]) ----
#pragma unroll
  for (int hb = 0; hb < 4; ++hb) {
    ushort4 ov;
    ov.x = f2bf(ot[hb][0] * inv);
    ov.y = f2bf(ot[hb][1] * inv);
    ov.z = f2bf(ot[hb][2] * inv);
    ov.w = f2bf(ot[hb][3] * inv);
    *(ushort4*)(o + (size_t)(b * 2048 + i0 + q15) * 1024 + h * 64 + hb * 16 + grp * 4) = ov;
  }
}

// ---------------- launcher ----------------
// ws budget (aliased by liveness): exactly 64 MB.
//   [0,       25165824)  : transposed weights (persistent)
//   [25165824,58720256)  : BIG   = qkvb (qkv->attn) then ff1 (fc1->fc2)
//   [58720256,67108864)  : SMALL = h1, then obuf, then h2
//   x1 lives in d_out (proj writes, ln2/fc2 read, fc2 overwrites in place).
extern "C" void kernel_launch(void* const* d_in, const int* in_sizes, int n_in,
                              void* d_out, int out_size, void* d_ws, size_t ws_size,
                              hipStream_t stream) {
  const float* x      = (const float*)d_in[0];
  const float* qkv_w  = (const float*)d_in[1];
  const float* qkv_b  = (const float*)d_in[2];
  const float* proj_w = (const float*)d_in[3];
  const float* proj_b = (const float*)d_in[4];
  const float* ln1_g  = (const float*)d_in[5];
  const float* ln1_b  = (const float*)d_in[6];
  const float* ln2_g  = (const float*)d_in[7];
  const float* ln2_b  = (const float*)d_in[8];
  const float* fc1_w  = (const float*)d_in[9];
  const float* fc1_b  = (const float*)d_in[10];
  const float* fc2_w  = (const float*)d_in[11];
  const float* fc2_b  = (const float*)d_in[12];
  float* out = (float*)d_out;

  char* ws = (char*)d_ws;
  u16* qkvw_t  = (u16*)(ws);                                  // 6291456 B
  u16* projw_t = (u16*)(ws + 6291456);                        // 2097152 B
  u16* fc1w_t  = (u16*)(ws + 8388608);                        // 8388608 B
  u16* fc2w_t  = (u16*)(ws + 16777216);                       // 8388608 B
  char* BIG    = ws + 25165824;                               // 33554432 B
  char* SMALL  = ws + 58720256;                               // 8388608 B
  u16* qkvb = (u16*)BIG;     // 4096x3072 bf16 (24 MB)
  u16* ff1  = (u16*)BIG;     // 4096x4096 bf16 (32 MB), after qkvb dead
  u16* h1   = (u16*)SMALL;   // 4096x1024 bf16
  u16* obuf = (u16*)SMALL;   // after h1 dead
  u16* h2   = (u16*)SMALL;   // after obuf dead
  float* x1 = out;           // 4096x1024 f32 in d_out

  // weight transposes (fp32 [K,N] -> bf16 [N,K])
  wt_kernel<<<dim3(96, 32), 256, 0, stream>>>(qkv_w, qkvw_t, 1024, 3072);
  wt_kernel<<<dim3(32, 32), 256, 0, stream>>>(proj_w, projw_t, 1024, 1024);
  wt_kernel<<<dim3(128, 32), 256, 0, stream>>>(fc1_w, fc1w_t, 1024, 4096);
  wt_kernel<<<dim3(32, 128), 256, 0, stream>>>(fc2_w, fc2w_t, 4096, 1024);

  ln_kernel<<<4096, 256, 0, stream>>>(x, ln1_g, ln1_b, h1);
  gemm_kernel<0, 0, 0, 1><<<dim3(32, 24), 256, 0, stream>>>(h1, qkvw_t, qkv_b, nullptr, nullptr, qkvb, 4096, 3072, 1024);
  attn_kernel<<<dim3(32, 32), 256, 0, stream>>>(qkvb, obuf);
  gemm_kernel<0, 1, 1, 0><<<dim3(32, 8), 256, 0, stream>>>(obuf, projw_t, proj_b, x, x1, nullptr, 4096, 1024, 1024);
  ln_kernel<<<4096, 256, 0, stream>>>(x1, ln2_g, ln2_b, h2);
  gemm_kernel<1, 0, 0, 1><<<dim3(32, 32), 256, 0, stream>>>(h2, fc1w_t, fc1_b, nullptr, nullptr, ff1, 4096, 4096, 1024);
  gemm_kernel<0, 1, 1, 0><<<dim3(32, 8), 256, 0, stream>>>(ff1, fc2w_t, fc2_b, x1, out, nullptr, 4096, 1024, 4096);
}

// Round 4
// 332.114 us; speedup vs baseline: 1.1671x; 1.1671x over previous
//
#include <hip/hip_runtime.h>
#include <stdint.h>

typedef unsigned short u16;
typedef __attribute__((ext_vector_type(8))) short bf16x8;
typedef __attribute__((ext_vector_type(4))) float f32x4;

__device__ __forceinline__ u16 f2bf(float f) {
  union { float f; unsigned u; } x; x.f = f;
  unsigned r = x.u + 0x7fffu + ((x.u >> 16) & 1u);
  return (u16)(r >> 16);
}

#define GLOAD16(g, l) __builtin_amdgcn_global_load_lds( \
    (const __attribute__((address_space(1))) unsigned int*)(g), \
    (__attribute__((address_space(3))) unsigned int*)(l), 16, 0, 0)

// ---------------- weight transpose fp32[K,N] -> bf16[N,K] ----------------
__global__ __launch_bounds__(256) void wt_kernel(const float* __restrict__ W,
                                                 u16* __restrict__ Wt, int K, int N) {
  __shared__ float tile[32][33];
  int tx = threadIdx.x & 31, ty = threadIdx.x >> 5;
  int n0 = blockIdx.x * 32, k0 = blockIdx.y * 32;
#pragma unroll
  for (int i = 0; i < 32; i += 8)
    tile[ty + i][tx] = W[(size_t)(k0 + ty + i) * N + n0 + tx];
  __syncthreads();
#pragma unroll
  for (int i = 0; i < 32; i += 8)
    Wt[(size_t)(n0 + ty + i) * K + k0 + tx] = f2bf(tile[tx][ty + i]);
}

// ---------------- LayerNorm fp32 -> bf16, D=1024 ----------------
__global__ __launch_bounds__(256) void ln_kernel(const float* __restrict__ x,
                                                 const float* __restrict__ g,
                                                 const float* __restrict__ be,
                                                 u16* __restrict__ out) {
  int row = blockIdx.x, t = threadIdx.x;
  const float4 v = ((const float4*)(x + (size_t)row * 1024))[t];
  float s = v.x + v.y + v.z + v.w;
#pragma unroll
  for (int m = 1; m < 64; m <<= 1) s += __shfl_xor(s, m);
  __shared__ float p1[4], p2[4];
  int wid = t >> 6, lane = t & 63;
  if (lane == 0) p1[wid] = s;
  __syncthreads();
  float mean = (p1[0] + p1[1] + p1[2] + p1[3]) * (1.f / 1024.f);
  float a0 = v.x - mean, a1 = v.y - mean, a2 = v.z - mean, a3 = v.w - mean;
  float ss = a0 * a0 + a1 * a1 + a2 * a2 + a3 * a3;
#pragma unroll
  for (int m = 1; m < 64; m <<= 1) ss += __shfl_xor(ss, m);
  if (lane == 0) p2[wid] = ss;
  __syncthreads();
  float var = (p2[0] + p2[1] + p2[2] + p2[3]) * (1.f / 1024.f);
  float rs = rsqrtf(var + 1e-5f);
  const float4 gg = ((const float4*)g)[t];
  const float4 bb = ((const float4*)be)[t];
  ushort4 ov;
  ov.x = f2bf(a0 * rs * gg.x + bb.x);
  ov.y = f2bf(a1 * rs * gg.y + bb.y);
  ov.z = f2bf(a2 * rs * gg.z + bb.z);
  ov.w = f2bf(a3 * rs * gg.w + bb.w);
  *(ushort4*)(out + (size_t)row * 1024 + t * 4) = ov;
}

// ---------------- bf16 MFMA GEMM: C[M,N] = A[M,K] * Bt[N,K]^T + bias ----------------
// 128xBN tile, BK=64, 4 waves, 2-phase double-buffered global_load_lds pipeline,
// XOR-swizzled LDS (both-sides).
template <int BN, int GELU_F, int HAS_RES, int OUT_F32, int OUT_BF16>
__global__ __launch_bounds__(256) void gemm_kernel(
    const u16* __restrict__ A, const u16* __restrict__ Bt,
    const float* __restrict__ bias, const float* __restrict__ res,
    float* __restrict__ outf, u16* __restrict__ outb, int M, int N, int K) {
  __shared__ u16 lA[2][128 * 64];
  __shared__ u16 lB[2][BN * 64];
  const int t = threadIdx.x, lane = t & 63, wid = t >> 6;
  const int bm = blockIdx.x, bn = blockIdx.y;
  constexpr int FM = (BN == 128) ? 4 : 2;       // 16-row fragments per wave
  const int wr = (BN == 128) ? (wid >> 1) : wid;
  const int wc = (BN == 128) ? (wid & 1) : 0;
  f32x4 acc[FM][4] = {};

  const int nkt = K >> 6;

  auto stage = [&](int buf, int kt) {
#pragma unroll
    for (int r = 0; r < 4; ++r) {
      int f = (r * 256 + t) * 16;                 // linear LDS byte offset
      int fs = f ^ (((f >> 7) & 7) << 4);         // inverse-swizzled source
      int row = fs >> 7;
      int kb = (fs & 127) >> 1;
      GLOAD16(A + (size_t)(bm * 128 + row) * K + kt * 64 + kb,
              ((char*)&lA[buf][0]) + (r * 256 + wid * 64) * 16);
    }
#pragma unroll
    for (int r = 0; r < BN / 32; ++r) {
      int f = (r * 256 + t) * 16;
      int fs = f ^ (((f >> 7) & 7) << 4);
      int row = fs >> 7;
      int kb = (fs & 127) >> 1;
      GLOAD16(Bt + (size_t)(bn * BN + row) * K + kt * 64 + kb,
              ((char*)&lB[buf][0]) + (r * 256 + wid * 64) * 16);
    }
  };

  stage(0, 0);
  __syncthreads();

  for (int kt = 0; kt < nkt; ++kt) {
    const int cur = kt & 1;
    if (kt + 1 < nkt) stage(cur ^ 1, kt + 1);     // issue next-tile loads early
#pragma unroll
    for (int kk = 0; kk < 2; ++kk) {
      bf16x8 af[FM], bfr[4];
#pragma unroll
      for (int fm = 0; fm < FM; ++fm) {
        int row = wr * (FM * 16) + fm * 16 + (lane & 15);
        int k = kk * 32 + (lane >> 4) * 8;
        af[fm] = *(const bf16x8*)((const char*)&lA[cur][0] + ((row * 128 + k * 2) ^ ((row & 7) << 4)));
      }
#pragma unroll
      for (int fn = 0; fn < 4; ++fn) {
        int row = wc * 64 + fn * 16 + (lane & 15);
        int k = kk * 32 + (lane >> 4) * 8;
        bfr[fn] = *(const bf16x8*)((const char*)&lB[cur][0] + ((row * 128 + k * 2) ^ ((row & 7) << 4)));
      }
#pragma unroll
      for (int fm = 0; fm < FM; ++fm)
#pragma unroll
        for (int fn = 0; fn < 4; ++fn)
          acc[fm][fn] = __builtin_amdgcn_mfma_f32_16x16x32_bf16(af[fm], bfr[fn], acc[fm][fn], 0, 0, 0);
    }
    __syncthreads();   // drains vmcnt (next tile landed) + protects cur from overwrite
  }

#pragma unroll
  for (int fm = 0; fm < FM; ++fm) {
#pragma unroll
    for (int fn = 0; fn < 4; ++fn) {
      int col = bn * BN + wc * 64 + fn * 16 + (lane & 15);
      float bcol = bias[col];
#pragma unroll
      for (int r = 0; r < 4; ++r) {
        int row = bm * 128 + wr * (FM * 16) + fm * 16 + (lane >> 4) * 4 + r;
        float v = acc[fm][fn][r] + bcol;
        if constexpr (GELU_F) v = 0.5f * v * (1.0f + erff(v * 0.70710678118654752f));
        size_t idx = (size_t)row * N + col;
        if constexpr (HAS_RES) v += res[idx];
        if constexpr (OUT_F32) outf[idx] = v;
        if constexpr (OUT_BF16) outb[idx] = f2bf(v);
      }
    }
  }
}

// ---------------- attention: ALiBi sliding-window causal, MFMA ----------------
// grid: (qtile 0..31, bh 0..31); block 256 = 4 waves, each wave 16 queries.
// K and V time-share one LDS region (K live only in QK^T, V only in PV):
// 80 KB total -> 2 blocks/CU. NaN-proof: finite sentinel, lV fully staged.
__global__ __launch_bounds__(256) void attn_kernel(const u16* __restrict__ qkv,
                                                   u16* __restrict__ o) {
  __shared__ u16 kvbuf[22016];      // 44 KB: K[320][64] swizzled, then V^T[64][344]
  __shared__ u16 lP[4][16 * 296];   // per-wave P [q][key 288], padded, 37 KB
  u16* lK = kvbuf;
  u16* lV = kvbuf;
  const int t = threadIdx.x, lane = t & 63, w = t >> 6;
  const int qtile = blockIdx.x, bh = blockIdx.y, b = bh >> 4, h = bh & 15;
  const int kbase = qtile * 64 - 256;
  const size_t bq = (size_t)b * 2048 * 3072;
  const float NEGBIG = -1e30f;

  // ---- phase 1: stage K (swizzled, keys 0..319) ----
  for (int r = 0; r < 10; ++r) {
    int jl = r * 32 + (t >> 3);      // 0..319
    int d0 = (t & 7) * 8;
    int jg = kbase + jl;
    uint4 kv;
    if (jg >= 0 && jg < 2048)
      kv = *(const uint4*)(qkv + bq + (size_t)jg * 3072 + 1024 + h * 64 + d0);
    else
      kv = make_uint4(0, 0, 0, 0);
    *(uint4*)((char*)lK + ((jl * 128 + d0 * 2) ^ ((jl & 7) << 4))) = kv;
  }
  __syncthreads();

  const int i0 = qtile * 64 + w * 16;
  const int q15 = lane & 15, grp = lane >> 4;
  // Q fragments in registers (B-operand of S^T mfma)
  const u16* qrow = qkv + bq + (size_t)(i0 + q15) * 3072 + h * 64;
  bf16x8 qf0 = *(const bf16x8*)(qrow + grp * 8);
  bf16x8 qf1 = *(const bf16x8*)(qrow + 32 + grp * 8);

  // ---- S^T = K * Q^T over 17 key tiles ----
  f32x4 st[17];
#pragma unroll
  for (int tt = 0; tt < 17; ++tt) {
    st[tt] = f32x4{0.f, 0.f, 0.f, 0.f};
    int klb = w * 16 + tt * 16;
#pragma unroll
    for (int kk = 0; kk < 2; ++kk) {
      int row = klb + q15;
      int k = kk * 32 + grp * 8;
      bf16x8 kf = *(const bf16x8*)((const char*)lK + ((row * 128 + k * 2) ^ ((row & 7) << 4)));
      st[tt] = __builtin_amdgcn_mfma_f32_16x16x32_bf16(kf, (kk ? qf1 : qf0), st[tt], 0, 0, 0);
    }
  }

  // ---- mask + alibi + softmax (reduce over keys: regs, tiles, lane-groups) ----
  const float slope = exp2f(-0.5f * (float)(h + 1));
  const int qg = i0 + q15;
  float mx = NEGBIG;
#pragma unroll
  for (int tt = 0; tt < 17; ++tt) {
    int kb = kbase + w * 16 + tt * 16;
#pragma unroll
    for (int r = 0; r < 4; ++r) {
      int key = kb + grp * 4 + r;
      float s = st[tt][r] * 0.125f + slope * (float)(key - qg);
      bool valid = (key >= 0) && (key <= qg) && (qg - key < 256);
      s = valid ? s : NEGBIG;
      st[tt][r] = s;
      mx = fmaxf(mx, s);
    }
  }
  mx = fmaxf(mx, __shfl_xor(mx, 16));
  mx = fmaxf(mx, __shfl_xor(mx, 32));
  float sum = 0.f;
#pragma unroll
  for (int tt = 0; tt < 17; ++tt)
#pragma unroll
    for (int r = 0; r < 4; ++r) {
      float p = __expf(st[tt][r] - mx);   // sentinel - finite -> underflow -> 0
      st[tt][r] = p;
      sum += p;
    }
  sum += __shfl_xor(sum, 16);
  sum += __shfl_xor(sum, 32);
  const float inv = 1.0f / sum;           // sum >= 1 (diagonal always valid)

  // ---- write P (bf16, unnormalized) to per-wave LDS (own wave reads it) ----
  u16* Pw = &lP[w][0];
#pragma unroll
  for (int tt = 0; tt < 17; ++tt) {
    unsigned u0 = ((unsigned)f2bf(st[tt][1]) << 16) | f2bf(st[tt][0]);
    unsigned u1 = ((unsigned)f2bf(st[tt][3]) << 16) | f2bf(st[tt][2]);
    uint2 uu; uu.x = u0; uu.y = u1;
    *(uint2*)(Pw + q15 * 296 + tt * 16 + grp * 4) = uu;
  }
  { uint2 z; z.x = 0; z.y = 0; *(uint2*)(Pw + q15 * 296 + 272 + grp * 4) = z; }

  __syncthreads();   // all QK^T reads of lK done -> safe to overwrite with V

  // ---- phase 2: stage V^T (keys 0..335, zero-filled outside) ----
  for (int r = 0; r < 11; ++r) {
    int jl = r * 32 + (t >> 3);      // 0..351
    int d0 = (t & 7) * 8;
    int jg = kbase + jl;
    if (jl < 336) {
      uint4 vv;
      if (jg >= 0 && jg < 2048)
        vv = *(const uint4*)(qkv + bq + (size_t)jg * 3072 + 2048 + h * 64 + d0);
      else
        vv = make_uint4(0, 0, 0, 0);
      const u16* vs = (const u16*)&vv;
#pragma unroll
      for (int u = 0; u < 8; ++u) lV[(d0 + u) * 344 + jl] = vs[u];
    }
  }
  __syncthreads();

  // ---- O^T = V^T * P^T over 9 key chunks of 32 ----
  f32x4 ot[4] = {};
#pragma unroll
  for (int c = 0; c < 9; ++c) {
    bf16x8 pf = *(const bf16x8*)(Pw + q15 * 296 + c * 32 + grp * 8);
#pragma unroll
    for (int hb = 0; hb < 4; ++hb) {
      bf16x8 vf = *(const bf16x8*)(lV + (hb * 16 + q15) * 344 + w * 16 + c * 32 + grp * 8);
      ot[hb] = __builtin_amdgcn_mfma_f32_16x16x32_bf16(vf, pf, ot[hb], 0, 0, 0);
    }
  }

  // ---- normalize + store O (bf16 [4096][1024]) ----
#pragma unroll
  for (int hb = 0; hb < 4; ++hb) {
    ushort4 ov;
    ov.x = f2bf(ot[hb][0] * inv);
    ov.y = f2bf(ot[hb][1] * inv);
    ov.z = f2bf(ot[hb][2] * inv);
    ov.w = f2bf(ot[hb][3] * inv);
    *(ushort4*)(o + (size_t)(b * 2048 + i0 + q15) * 1024 + h * 64 + hb * 16 + grp * 4) = ov;
  }
}

// ---------------- launcher ----------------
// ws budget (aliased by liveness): exactly 64 MB.
//   [0,       25165824)  : transposed weights (persistent)
//   [25165824,58720256)  : BIG   = qkvb (qkv->attn) then ff1 (fc1->fc2)
//   [58720256,67108864)  : SMALL = h1, then obuf, then h2
//   x1 lives in d_out (proj writes, ln2/fc2 read, fc2 overwrites in place).
extern "C" void kernel_launch(void* const* d_in, const int* in_sizes, int n_in,
                              void* d_out, int out_size, void* d_ws, size_t ws_size,
                              hipStream_t stream) {
  const float* x      = (const float*)d_in[0];
  const float* qkv_w  = (const float*)d_in[1];
  const float* qkv_b  = (const float*)d_in[2];
  const float* proj_w = (const float*)d_in[3];
  const float* proj_b = (const float*)d_in[4];
  const float* ln1_g  = (const float*)d_in[5];
  const float* ln1_b  = (const float*)d_in[6];
  const float* ln2_g  = (const float*)d_in[7];
  const float* ln2_b  = (const float*)d_in[8];
  const float* fc1_w  = (const float*)d_in[9];
  const float* fc1_b  = (const float*)d_in[10];
  const float* fc2_w  = (const float*)d_in[11];
  const float* fc2_b  = (const float*)d_in[12];
  float* out = (float*)d_out;

  char* ws = (char*)d_ws;
  u16* qkvw_t  = (u16*)(ws);                                  // 6291456 B
  u16* projw_t = (u16*)(ws + 6291456);                        // 2097152 B
  u16* fc1w_t  = (u16*)(ws + 8388608);                        // 8388608 B
  u16* fc2w_t  = (u16*)(ws + 16777216);                       // 8388608 B
  char* BIG    = ws + 25165824;                               // 33554432 B
  char* SMALL  = ws + 58720256;                               // 8388608 B
  u16* qkvb = (u16*)BIG;     // 4096x3072 bf16 (24 MB)
  u16* ff1  = (u16*)BIG;     // 4096x4096 bf16 (32 MB), after qkvb dead
  u16* h1   = (u16*)SMALL;   // 4096x1024 bf16
  u16* obuf = (u16*)SMALL;   // after h1 dead
  u16* h2   = (u16*)SMALL;   // after obuf dead
  float* x1 = out;           // 4096x1024 f32 in d_out

  // weight transposes (fp32 [K,N] -> bf16 [N,K])
  wt_kernel<<<dim3(96, 32), 256, 0, stream>>>(qkv_w, qkvw_t, 1024, 3072);
  wt_kernel<<<dim3(32, 32), 256, 0, stream>>>(proj_w, projw_t, 1024, 1024);
  wt_kernel<<<dim3(128, 32), 256, 0, stream>>>(fc1_w, fc1w_t, 1024, 4096);
  wt_kernel<<<dim3(32, 128), 256, 0, stream>>>(fc2_w, fc2w_t, 4096, 1024);

  ln_kernel<<<4096, 256, 0, stream>>>(x, ln1_g, ln1_b, h1);
  gemm_kernel<128, 0, 0, 0, 1><<<dim3(32, 24), 256, 0, stream>>>(h1, qkvw_t, qkv_b, nullptr, nullptr, qkvb, 4096, 3072, 1024);
  attn_kernel<<<dim3(32, 32), 256, 0, stream>>>(qkvb, obuf);
  gemm_kernel<64, 0, 1, 1, 0><<<dim3(32, 16), 256, 0, stream>>>(obuf, projw_t, proj_b, x, x1, nullptr, 4096, 1024, 1024);
  ln_kernel<<<4096, 256, 0, stream>>>(x1, ln2_g, ln2_b, h2);
  gemm_kernel<128, 1, 0, 0, 1><<<dim3(32, 32), 256, 0, stream>>>(h2, fc1w_t, fc1_b, nullptr, nullptr, ff1, 4096, 4096, 1024);
  gemm_kernel<64, 0, 1, 1, 0><<<dim3(32, 16), 256, 0, stream>>>(ff1, fc2w_t, fc2_b, x1, out, nullptr, 4096, 1024, 4096);
}

// Round 7
// 324.960 us; speedup vs baseline: 1.1928x; 1.0220x over previous
//
#include <hip/hip_runtime.h>
#include <stdint.h>

typedef unsigned short u16;
typedef __attribute__((ext_vector_type(8))) short bf16x8;
typedef __attribute__((ext_vector_type(4))) float f32x4;

__device__ __forceinline__ u16 f2bf(float f) {
  union { float f; unsigned u; } x; x.f = f;
  unsigned r = x.u + 0x7fffu + ((x.u >> 16) & 1u);
  return (u16)(r >> 16);
}

__device__ __forceinline__ float gelu_fast(float v) {
  // tanh-form GELU; |err| vs exact erf-GELU ~1e-3 (absorbed by bf16 slack)
  float y = 0.7978845608f * (v + 0.044715f * v * v * v);
  float e = __expf(2.0f * y);
  float th = 1.0f - 2.0f / (e + 1.0f);
  return 0.5f * v * (1.0f + th);
}

#define GLOAD16(g, l) __builtin_amdgcn_global_load_lds( \
    (const __attribute__((address_space(1))) unsigned int*)(g), \
    (__attribute__((address_space(3))) unsigned int*)(l), 16, 0, 0)

// ---------------- weight transpose fp32[K,N] -> bf16[N,K] ----------------
__global__ __launch_bounds__(256) void wt_kernel(const float* __restrict__ W,
                                                 u16* __restrict__ Wt, int K, int N) {
  __shared__ float tile[32][33];
  int tx = threadIdx.x & 31, ty = threadIdx.x >> 5;
  int n0 = blockIdx.x * 32, k0 = blockIdx.y * 32;
#pragma unroll
  for (int i = 0; i < 32; i += 8)
    tile[ty + i][tx] = W[(size_t)(k0 + ty + i) * N + n0 + tx];
  __syncthreads();
#pragma unroll
  for (int i = 0; i < 32; i += 8)
    Wt[(size_t)(n0 + ty + i) * K + k0 + tx] = f2bf(tile[tx][ty + i]);
}

// ---------------- LayerNorm fp32 -> bf16, D=1024 ----------------
__global__ __launch_bounds__(256) void ln_kernel(const float* __restrict__ x,
                                                 const float* __restrict__ g,
                                                 const float* __restrict__ be,
                                                 u16* __restrict__ out) {
  int row = blockIdx.x, t = threadIdx.x;
  const float4 v = ((const float4*)(x + (size_t)row * 1024))[t];
  float s = v.x + v.y + v.z + v.w;
#pragma unroll
  for (int m = 1; m < 64; m <<= 1) s += __shfl_xor(s, m);
  __shared__ float p1[4], p2[4];
  int wid = t >> 6, lane = t & 63;
  if (lane == 0) p1[wid] = s;
  __syncthreads();
  float mean = (p1[0] + p1[1] + p1[2] + p1[3]) * (1.f / 1024.f);
  float a0 = v.x - mean, a1 = v.y - mean, a2 = v.z - mean, a3 = v.w - mean;
  float ss = a0 * a0 + a1 * a1 + a2 * a2 + a3 * a3;
#pragma unroll
  for (int m = 1; m < 64; m <<= 1) ss += __shfl_xor(ss, m);
  if (lane == 0) p2[wid] = ss;
  __syncthreads();
  float var = (p2[0] + p2[1] + p2[2] + p2[3]) * (1.f / 1024.f);
  float rs = rsqrtf(var + 1e-5f);
  const float4 gg = ((const float4*)g)[t];
  const float4 bb = ((const float4*)be)[t];
  ushort4 ov;
  ov.x = f2bf(a0 * rs * gg.x + bb.x);
  ov.y = f2bf(a1 * rs * gg.y + bb.y);
  ov.z = f2bf(a2 * rs * gg.z + bb.z);
  ov.w = f2bf(a3 * rs * gg.w + bb.w);
  *(ushort4*)(out + (size_t)row * 1024 + t * 4) = ov;
}

// ======== 256x256 8-phase bf16 GEMM (T1+T2+T3+T4+T5), C = A * Bt^T + bias ========
// 512 threads = 8 waves (2M x 4N), per-wave 128x64. BK=64, even K-tiles in slot0,
// odd in slot1. Per phase: {ds_read subtile || stage half-tile} -> barrier ->
// setprio(1) 16 MFMA setprio(0) -> [vmcnt(6) at P4/P8] -> barrier.
#define SB __builtin_amdgcn_sched_barrier(0)
#define BAR __builtin_amdgcn_s_barrier()

#define LDA(SLOT, RH) \
  _Pragma("unroll") for (int j = 0; j < 4; ++j) \
  _Pragma("unroll") for (int kk = 0; kk < 2; ++kk) { \
    int row_ = wm * 128 + (RH) * 64 + j * 16 + (lane & 15); \
    int byte_ = (row_ * 128 + (kk * 32 + (lane >> 4) * 8) * 2) ^ ((row_ & 7) << 4); \
    a[j][kk] = *(const bf16x8*)((const char*)&lA[SLOT][0] + byte_); }

#define LDB(SLOT, CH, BREG) \
  _Pragma("unroll") for (int fn = 0; fn < 2; ++fn) \
  _Pragma("unroll") for (int kk = 0; kk < 2; ++kk) { \
    int row_ = wn * 64 + (CH) * 32 + fn * 16 + (lane & 15); \
    int byte_ = (row_ * 128 + (kk * 32 + (lane >> 4) * 8) * 2) ^ ((row_ & 7) << 4); \
    BREG[fn][kk] = *(const bf16x8*)((const char*)&lB[SLOT][0] + byte_); }

#define QUAD(RH, CH, BREG) \
  _Pragma("unroll") for (int kk = 0; kk < 2; ++kk) \
  _Pragma("unroll") for (int j = 0; j < 4; ++j) \
  _Pragma("unroll") for (int fn = 0; fn < 2; ++fn) \
    acc[(RH) * 4 + j][(CH) * 2 + fn] = __builtin_amdgcn_mfma_f32_16x16x32_bf16( \
        a[j][kk], BREG[fn][kk], acc[(RH) * 4 + j][(CH) * 2 + fn], 0, 0, 0);

#define PH_SYNC1 SB; BAR; __builtin_amdgcn_s_setprio(1)
#define PH_SYNC2 __builtin_amdgcn_s_setprio(0); SB
#define PH_END BAR; SB

template <int GELU_F, int HAS_RES, int OUT_F32, int OUT_BF16>
__global__ __launch_bounds__(512, 2) void gemm256_kernel(
    const u16* __restrict__ A, const u16* __restrict__ Bt,
    const float* __restrict__ bias, const float* __restrict__ res,
    float* __restrict__ outf, u16* __restrict__ outb, int M, int N, int K, int nbn) {
  __shared__ u16 lA[2][256 * 64];   // 64 KB
  __shared__ u16 lB[2][256 * 64];   // 64 KB
  const int t = threadIdx.x, lane = t & 63, wid = t >> 6;
  const int wm = wid >> 2, wn = wid & 3;

  // bijective XCD swizzle (m204)
  const int nwg = gridDim.x;
  const int q = nwg >> 3, rr = nwg & 7;
  const int xcd = blockIdx.x & 7, oin = blockIdx.x >> 3;
  const int swz = (xcd < rr ? xcd * (q + 1) : rr * (q + 1) + (xcd - rr) * q) + oin;
  const int bm = swz / nbn, bn = swz % nbn;

  const u16* Abase = A + (size_t)(bm * 256) * K;
  const u16* Bbase = Bt + (size_t)(bn * 256) * K;

  auto stA = [&](int slot, int hh, int kt) {
#pragma unroll
    for (int r = 0; r < 2; ++r) {
      int f = hh * 16384 + (r * 512 + t) * 16;
      int fs = f ^ (((f >> 7) & 7) << 4);
      int row = fs >> 7, kb = (fs & 127) >> 1;
      GLOAD16(Abase + (size_t)row * K + kt * 64 + kb, (char*)&lA[slot][0] + f);
    }
  };
  auto stB = [&](int slot, int hh, int kt) {
#pragma unroll
    for (int r = 0; r < 2; ++r) {
      int f = hh * 16384 + (r * 512 + t) * 16;
      int fs = f ^ (((f >> 7) & 7) << 4);
      int row = fs >> 7, kb = (fs & 127) >> 1;
      GLOAD16(Bbase + (size_t)row * K + kt * 64 + kb, (char*)&lB[slot][0] + f);
    }
  };

  f32x4 acc[8][4] = {};
  bf16x8 a[4][2], b0[2][2], b1[2][2];

  const int nkt = K >> 6, niter = nkt >> 1;

  // prologue: K-tile0 fully; K-tile1 B halves + A-h0 (A-h1 staged at P1)
  stA(0, 0, 0); stA(0, 1, 0); stB(0, 0, 0); stB(0, 1, 0);
  stB(1, 0, 1); stB(1, 1, 1); stA(1, 0, 1);
  asm volatile("s_waitcnt vmcnt(6)" ::: "memory");
  BAR; SB;

  for (int i = 0; i < niter; ++i) {
    const int kt1 = 2 * i + 1, n0 = 2 * i + 2, n1 = 2 * i + 3;
    const bool lastI = (i == niter - 1);
    // ---- P1: quadrant (rh0,ch0) of slot0 ----
    LDA(0, 0); LDB(0, 0, b0);
    stA(1, 1, kt1);                       // complete kt1 staging (slot1-A freed prev P7)
    PH_SYNC1; QUAD(0, 0, b0); PH_SYNC2; PH_END;
    // ---- P2: (rh0,ch1) ----
    LDB(0, 1, b1);
    PH_SYNC1; QUAD(0, 1, b1); PH_SYNC2; PH_END;
    // ---- P3: (rh1,ch0) ----
    LDA(0, 1);
    if (!lastI) stB(0, 0, n0);            // slot0-B freed after P2
    PH_SYNC1; QUAD(1, 0, b0); PH_SYNC2; PH_END;
    // ---- P4: (rh1,ch1) ----
    if (!lastI) { stB(0, 1, n0); stA(0, 0, n0); }   // slot0-A freed after P3
    PH_SYNC1; QUAD(1, 1, b1); PH_SYNC2;
    if (lastI) { asm volatile("s_waitcnt vmcnt(0)" ::: "memory"); }
    else       { asm volatile("s_waitcnt vmcnt(6)" ::: "memory"); }
    PH_END;
    // ---- P5: (rh0,ch0) of slot1 ----
    LDA(1, 0); LDB(1, 0, b0);
    if (!lastI) stA(0, 1, n0);
    PH_SYNC1; QUAD(0, 0, b0); PH_SYNC2; PH_END;
    // ---- P6: (rh0,ch1) ----
    LDB(1, 1, b1);
    PH_SYNC1; QUAD(0, 1, b1); PH_SYNC2; PH_END;
    // ---- P7: (rh1,ch0) ----
    LDA(1, 1);
    if (!lastI) stB(1, 0, n1);            // slot1-B freed after P6
    PH_SYNC1; QUAD(1, 0, b0); PH_SYNC2; PH_END;
    // ---- P8: (rh1,ch1) ----
    if (!lastI) { stB(1, 1, n1); stA(1, 0, n1); }   // slot1-A freed after P7
    PH_SYNC1; QUAD(1, 1, b1); PH_SYNC2;
    if (lastI) { asm volatile("s_waitcnt vmcnt(0)" ::: "memory"); }
    else       { asm volatile("s_waitcnt vmcnt(6)" ::: "memory"); }
    PH_END;
  }

  // ---- epilogue ----
#pragma unroll
  for (int fm = 0; fm < 8; ++fm) {
#pragma unroll
    for (int fn = 0; fn < 4; ++fn) {
      int col = bn * 256 + wn * 64 + fn * 16 + (lane & 15);
      float bcol = bias[col];
#pragma unroll
      for (int r = 0; r < 4; ++r) {
        int row = bm * 256 + wm * 128 + fm * 16 + (lane >> 4) * 4 + r;
        float v = acc[fm][fn][r] + bcol;
        if constexpr (GELU_F) v = gelu_fast(v);
        size_t idx = (size_t)row * N + col;
        if constexpr (HAS_RES) v += res[idx];
        if constexpr (OUT_F32) outf[idx] = v;
        if constexpr (OUT_BF16) outb[idx] = f2bf(v);
      }
    }
  }
}

// ---------------- 2-phase bf16 MFMA GEMM (kept for proj / fc2, BN=64) ----------------
template <int BN, int GELU_F, int HAS_RES, int OUT_F32, int OUT_BF16>
__global__ __launch_bounds__(256) void gemm_kernel(
    const u16* __restrict__ A, const u16* __restrict__ Bt,
    const float* __restrict__ bias, const float* __restrict__ res,
    float* __restrict__ outf, u16* __restrict__ outb, int M, int N, int K) {
  __shared__ u16 lA[2][128 * 64];
  __shared__ u16 lB[2][BN * 64];
  const int t = threadIdx.x, lane = t & 63, wid = t >> 6;
  const int bm = blockIdx.x, bn = blockIdx.y;
  constexpr int FM = (BN == 128) ? 4 : 2;
  const int wr = (BN == 128) ? (wid >> 1) : wid;
  const int wc = (BN == 128) ? (wid & 1) : 0;
  f32x4 acc[FM][4] = {};

  const int nkt = K >> 6;

  auto stage = [&](int buf, int kt) {
#pragma unroll
    for (int r = 0; r < 4; ++r) {
      int f = (r * 256 + t) * 16;
      int fs = f ^ (((f >> 7) & 7) << 4);
      int row = fs >> 7;
      int kb = (fs & 127) >> 1;
      GLOAD16(A + (size_t)(bm * 128 + row) * K + kt * 64 + kb,
              ((char*)&lA[buf][0]) + (r * 256 + wid * 64) * 16);
    }
#pragma unroll
    for (int r = 0; r < BN / 32; ++r) {
      int f = (r * 256 + t) * 16;
      int fs = f ^ (((f >> 7) & 7) << 4);
      int row = fs >> 7;
      int kb = (fs & 127) >> 1;
      GLOAD16(Bt + (size_t)(bn * BN + row) * K + kt * 64 + kb,
              ((char*)&lB[buf][0]) + (r * 256 + wid * 64) * 16);
    }
  };

  stage(0, 0);
  __syncthreads();

  for (int kt = 0; kt < nkt; ++kt) {
    const int cur = kt & 1;
    if (kt + 1 < nkt) stage(cur ^ 1, kt + 1);
#pragma unroll
    for (int kk = 0; kk < 2; ++kk) {
      bf16x8 af[FM], bfr[4];
#pragma unroll
      for (int fm = 0; fm < FM; ++fm) {
        int row = wr * (FM * 16) + fm * 16 + (lane & 15);
        int k = kk * 32 + (lane >> 4) * 8;
        af[fm] = *(const bf16x8*)((const char*)&lA[cur][0] + ((row * 128 + k * 2) ^ ((row & 7) << 4)));
      }
#pragma unroll
      for (int fn = 0; fn < 4; ++fn) {
        int row = wc * 64 + fn * 16 + (lane & 15);
        int k = kk * 32 + (lane >> 4) * 8;
        bfr[fn] = *(const bf16x8*)((const char*)&lB[cur][0] + ((row * 128 + k * 2) ^ ((row & 7) << 4)));
      }
#pragma unroll
      for (int fm = 0; fm < FM; ++fm)
#pragma unroll
        for (int fn = 0; fn < 4; ++fn)
          acc[fm][fn] = __builtin_amdgcn_mfma_f32_16x16x32_bf16(af[fm], bfr[fn], acc[fm][fn], 0, 0, 0);
    }
    __syncthreads();
  }

#pragma unroll
  for (int fm = 0; fm < FM; ++fm) {
#pragma unroll
    for (int fn = 0; fn < 4; ++fn) {
      int col = bn * BN + wc * 64 + fn * 16 + (lane & 15);
      float bcol = bias[col];
#pragma unroll
      for (int r = 0; r < 4; ++r) {
        int row = bm * 128 + wr * (FM * 16) + fm * 16 + (lane >> 4) * 4 + r;
        float v = acc[fm][fn][r] + bcol;
        if constexpr (GELU_F) v = gelu_fast(v);
        size_t idx = (size_t)row * N + col;
        if constexpr (HAS_RES) v += res[idx];
        if constexpr (OUT_F32) outf[idx] = v;
        if constexpr (OUT_BF16) outb[idx] = f2bf(v);
      }
    }
  }
}

// ---------------- attention: ALiBi sliding-window causal, MFMA ----------------
__global__ __launch_bounds__(256) void attn_kernel(const u16* __restrict__ qkv,
                                                   u16* __restrict__ o) {
  __shared__ u16 kvbuf[22016];      // 44 KB: K[320][64] swizzled, then V^T[64][344]
  __shared__ u16 lP[4][16 * 296];   // per-wave P, 37 KB
  u16* lK = kvbuf;
  u16* lV = kvbuf;
  const int t = threadIdx.x, lane = t & 63, w = t >> 6;
  const int qtile = blockIdx.x, bh = blockIdx.y, b = bh >> 4, h = bh & 15;
  const int kbase = qtile * 64 - 256;
  const size_t bq = (size_t)b * 2048 * 3072;
  const float NEGBIG = -1e30f;

  // ---- phase 1: stage K (swizzled, keys 0..319) ----
  for (int r = 0; r < 10; ++r) {
    int jl = r * 32 + (t >> 3);
    int d0 = (t & 7) * 8;
    int jg = kbase + jl;
    uint4 kv;
    if (jg >= 0 && jg < 2048)
      kv = *(const uint4*)(qkv + bq + (size_t)jg * 3072 + 1024 + h * 64 + d0);
    else
      kv = make_uint4(0, 0, 0, 0);
    *(uint4*)((char*)lK + ((jl * 128 + d0 * 2) ^ ((jl & 7) << 4))) = kv;
  }
  __syncthreads();

  const int i0 = qtile * 64 + w * 16;
  const int q15 = lane & 15, grp = lane >> 4;
  const u16* qrow = qkv + bq + (size_t)(i0 + q15) * 3072 + h * 64;
  bf16x8 qf0 = *(const bf16x8*)(qrow + grp * 8);
  bf16x8 qf1 = *(const bf16x8*)(qrow + 32 + grp * 8);

  f32x4 st[17];
#pragma unroll
  for (int tt = 0; tt < 17; ++tt) {
    st[tt] = f32x4{0.f, 0.f, 0.f, 0.f};
    int klb = w * 16 + tt * 16;
#pragma unroll
    for (int kk = 0; kk < 2; ++kk) {
      int row = klb + q15;
      int k = kk * 32 + grp * 8;
      bf16x8 kf = *(const bf16x8*)((const char*)lK + ((row * 128 + k * 2) ^ ((row & 7) << 4)));
      st[tt] = __builtin_amdgcn_mfma_f32_16x16x32_bf16(kf, (kk ? qf1 : qf0), st[tt], 0, 0, 0);
    }
  }

  const float slope = exp2f(-0.5f * (float)(h + 1));
  const int qg = i0 + q15;
  float mx = NEGBIG;
#pragma unroll
  for (int tt = 0; tt < 17; ++tt) {
    int kb = kbase + w * 16 + tt * 16;
#pragma unroll
    for (int r = 0; r < 4; ++r) {
      int key = kb + grp * 4 + r;
      float s = st[tt][r] * 0.125f + slope * (float)(key - qg);
      bool valid = (key >= 0) && (key <= qg) && (qg - key < 256);
      s = valid ? s : NEGBIG;
      st[tt][r] = s;
      mx = fmaxf(mx, s);
    }
  }
  mx = fmaxf(mx, __shfl_xor(mx, 16));
  mx = fmaxf(mx, __shfl_xor(mx, 32));
  float sum = 0.f;
#pragma unroll
  for (int tt = 0; tt < 17; ++tt)
#pragma unroll
    for (int r = 0; r < 4; ++r) {
      float p = __expf(st[tt][r] - mx);
      st[tt][r] = p;
      sum += p;
    }
  sum += __shfl_xor(sum, 16);
  sum += __shfl_xor(sum, 32);
  const float inv = 1.0f / sum;

  u16* Pw = &lP[w][0];
#pragma unroll
  for (int tt = 0; tt < 17; ++tt) {
    unsigned u0 = ((unsigned)f2bf(st[tt][1]) << 16) | f2bf(st[tt][0]);
    unsigned u1 = ((unsigned)f2bf(st[tt][3]) << 16) | f2bf(st[tt][2]);
    uint2 uu; uu.x = u0; uu.y = u1;
    *(uint2*)(Pw + q15 * 296 + tt * 16 + grp * 4) = uu;
  }
  { uint2 z; z.x = 0; z.y = 0; *(uint2*)(Pw + q15 * 296 + 272 + grp * 4) = z; }

  __syncthreads();   // lK reads done -> overwrite with V

  for (int r = 0; r < 11; ++r) {
    int jl = r * 32 + (t >> 3);
    int d0 = (t & 7) * 8;
    int jg = kbase + jl;
    if (jl < 336) {
      uint4 vv;
      if (jg >= 0 && jg < 2048)
        vv = *(const uint4*)(qkv + bq + (size_t)jg * 3072 + 2048 + h * 64 + d0);
      else
        vv = make_uint4(0, 0, 0, 0);
      const u16* vs = (const u16*)&vv;
#pragma unroll
      for (int u = 0; u < 8; ++u) lV[(d0 + u) * 344 + jl] = vs[u];
    }
  }
  __syncthreads();

  f32x4 ot[4] = {};
#pragma unroll
  for (int c = 0; c < 9; ++c) {
    bf16x8 pf = *(const bf16x8*)(Pw + q15 * 296 + c * 32 + grp * 8);
#pragma unroll
    for (int hb = 0; hb < 4; ++hb) {
      bf16x8 vf = *(const bf16x8*)(lV + (hb * 16 + q15) * 344 + w * 16 + c * 32 + grp * 8);
      ot[hb] = __builtin_amdgcn_mfma_f32_16x16x32_bf16(vf, pf, ot[hb], 0, 0, 0);
    }
  }

#pragma unroll
  for (int hb = 0; hb < 4; ++hb) {
    ushort4 ov;
    ov.x = f2bf(ot[hb][0] * inv);
    ov.y = f2bf(ot[hb][1] * inv);
    ov.z = f2bf(ot[hb][2] * inv);
    ov.w = f2bf(ot[hb][3] * inv);
    *(ushort4*)(o + (size_t)(b * 2048 + i0 + q15) * 1024 + h * 64 + hb * 16 + grp * 4) = ov;
  }
}

// ---------------- launcher ----------------
// ws (aliased by liveness): 64 MB total.
//   [0,25165824): transposed weights | [25165824,58720256): BIG = qkvb then ff1
//   [58720256,67108864): SMALL = h1 / obuf / h2 | x1 lives in d_out.
extern "C" void kernel_launch(void* const* d_in, const int* in_sizes, int n_in,
                              void* d_out, int out_size, void* d_ws, size_t ws_size,
                              hipStream_t stream) {
  const float* x      = (const float*)d_in[0];
  const float* qkv_w  = (const float*)d_in[1];
  const float* qkv_b  = (const float*)d_in[2];
  const float* proj_w = (const float*)d_in[3];
  const float* proj_b = (const float*)d_in[4];
  const float* ln1_g  = (const float*)d_in[5];
  const float* ln1_b  = (const float*)d_in[6];
  const float* ln2_g  = (const float*)d_in[7];
  const float* ln2_b  = (const float*)d_in[8];
  const float* fc1_w  = (const float*)d_in[9];
  const float* fc1_b  = (const float*)d_in[10];
  const float* fc2_w  = (const float*)d_in[11];
  const float* fc2_b  = (const float*)d_in[12];
  float* out = (float*)d_out;

  char* ws = (char*)d_ws;
  u16* qkvw_t  = (u16*)(ws);
  u16* projw_t = (u16*)(ws + 6291456);
  u16* fc1w_t  = (u16*)(ws + 8388608);
  u16* fc2w_t  = (u16*)(ws + 16777216);
  char* BIG    = ws + 25165824;
  char* SMALL  = ws + 58720256;
  u16* qkvb = (u16*)BIG;
  u16* ff1  = (u16*)BIG;
  u16* h1   = (u16*)SMALL;
  u16* obuf = (u16*)SMALL;
  u16* h2   = (u16*)SMALL;
  float* x1 = out;

  wt_kernel<<<dim3(96, 32), 256, 0, stream>>>(qkv_w, qkvw_t, 1024, 3072);
  wt_kernel<<<dim3(32, 32), 256, 0, stream>>>(proj_w, projw_t, 1024, 1024);
  wt_kernel<<<dim3(128, 32), 256, 0, stream>>>(fc1_w, fc1w_t, 1024, 4096);
  wt_kernel<<<dim3(32, 128), 256, 0, stream>>>(fc2_w, fc2w_t, 4096, 1024);

  ln_kernel<<<4096, 256, 0, stream>>>(x, ln1_g, ln1_b, h1);
  gemm256_kernel<0, 0, 0, 1><<<192, 512, 0, stream>>>(h1, qkvw_t, qkv_b, nullptr, nullptr, qkvb, 4096, 3072, 1024, 12);
  attn_kernel<<<dim3(32, 32), 256, 0, stream>>>(qkvb, obuf);
  gemm_kernel<64, 0, 1, 1, 0><<<dim3(32, 16), 256, 0, stream>>>(obuf, projw_t, proj_b, x, x1, nullptr, 4096, 1024, 1024);
  ln_kernel<<<4096, 256, 0, stream>>>(x1, ln2_g, ln2_b, h2);
  gemm256_kernel<1, 0, 0, 1><<<256, 512, 0, stream>>>(h2, fc1w_t, fc1_b, nullptr, nullptr, ff1, 4096, 4096, 1024, 16);
  gemm_kernel<64, 0, 1, 1, 0><<<dim3(32, 16), 256, 0, stream>>>(ff1, fc2w_t, fc2_b, x1, out, nullptr, 4096, 1024, 4096);
}